// Round 9
// baseline (543.499 us; speedup 1.0000x reference)
//
#include <hip/hip_runtime.h>
#include <math.h>

#define HSTEP 0.1f
#define EPS_IN 1e-5f
#define BIGF 1e10f
#define DCF 3.79f

typedef float v4f __attribute__((ext_vector_type(4)));

// ---------------------------------------------------------------------------
// helpers
// ---------------------------------------------------------------------------
__device__ inline float block_sum1(float v, float* sred) {
    #pragma unroll
    for (int off = 32; off > 0; off >>= 1) v += __shfl_down(v, off);
    int wid = threadIdx.x >> 6;
    int nw  = blockDim.x >> 6;
    if ((threadIdx.x & 63) == 0) sred[wid] = v;
    __syncthreads();
    float total = 0.f;
    for (int i = 0; i < nw; ++i) total += sred[i];
    __syncthreads();
    return total;
}

__device__ inline float2 block_sum2(float a, float b, float2* sred) {
    #pragma unroll
    for (int off = 32; off > 0; off >>= 1) {
        a += __shfl_down(a, off);
        b += __shfl_down(b, off);
    }
    int wid = threadIdx.x >> 6;
    int nw  = blockDim.x >> 6;
    if ((threadIdx.x & 63) == 0) sred[wid] = make_float2(a, b);
    __syncthreads();
    float ta = 0.f, tb = 0.f;
    for (int i = 0; i < nw; ++i) { ta += sred[i].x; tb += sred[i].y; }
    __syncthreads();
    return make_float2(ta, tb);
}

// ---------------------------------------------------------------------------
// fused conv (optionally transposed weights) * mask -> masked instance norm
// -> relu -> optional skip add -> optional fused avg-pool (POOL) with
// optional fused upsample-on-read (UPS).  One block (1024 thr) per (b, co).
// Conv body verbatim round 2 (measured fastest); POOL/UPS semantics verified
// rounds 4/5.
// ---------------------------------------------------------------------------
template<int CIN, bool TR, bool UPS, bool POOL>
__global__ void __launch_bounds__(1024)
conv_in_relu_kernel(const float* __restrict__ xin, float* __restrict__ out,
                    const float* __restrict__ K, int Cout, int N,
                    const float* __restrict__ mask, const float* __restrict__ denom,
                    const float* __restrict__ skip, float* __restrict__ pool,
                    const float* __restrict__ mhalf)
{
    __shared__ float srow[2048];
    __shared__ float swt[CIN * 3];
    __shared__ float2 sred[16];

    const int b   = blockIdx.x / Cout;
    const int co  = blockIdx.x % Cout;
    const int tid = threadIdx.x;

    for (int i = tid; i < CIN * 3; i += blockDim.x) {
        int ci = i / 3, k = i % 3;
        swt[i] = TR ? K[((size_t)ci * Cout + co) * 3 + (2 - k)]
                    : K[((size_t)co * CIN + ci) * 3 + k];
    }
    __syncthreads();

    const int srcw = UPS ? (N >> 1) : N;
    const float* mrow = mask + (size_t)b * N;
    const float* xb   = xin + (size_t)b * CIN * srcw;
    float lsum = 0.f, lss = 0.f;
    for (int n = tid; n < N; n += 1024) {
        float acc = 0.f;
        #pragma unroll 8
        for (int ci = 0; ci < CIN; ++ci) {
            const float* src = xb + (size_t)ci * srcw;
            float xm, x0, xp;
            if (!UPS) {
                xm = (n > 0)     ? src[n - 1] : 0.f;
                x0 = src[n];
                xp = (n < N - 1) ? src[n + 1] : 0.f;
            } else {
                x0 = src[n >> 1] * mrow[n];
                xm = (n > 0)     ? src[(n - 1) >> 1] * mrow[n - 1] : 0.f;
                xp = (n < N - 1) ? src[(n + 1) >> 1] * mrow[n + 1] : 0.f;
            }
            acc = fmaf(swt[ci * 3 + 0], xm, acc);
            acc = fmaf(swt[ci * 3 + 1], x0, acc);
            acc = fmaf(swt[ci * 3 + 2], xp, acc);
        }
        float v = acc * mrow[n];
        srow[n] = v;
        lsum += v;
        lss  += v * v;
    }
    float dn = denom[b];
    float2 s = block_sum2(lsum, lss, sred);
    float mean = s.x / dn;
    float var  = s.y / dn - mean * mean;
    float inv  = 1.f / sqrtf(var + EPS_IN);

    float* orow = POOL ? nullptr : out + ((size_t)b * Cout + co) * N;
    const float* skrow = skip ? skip + ((size_t)b * Cout + co) * N : nullptr;
    for (int n = tid; n < N; n += 1024) {
        float mk = mrow[n];
        float zv = (srow[n] - mean * mk) * inv;
        float r  = fmaxf(zv, 0.f);
        if (skrow) r += skrow[n];
        if (POOL) srow[n] = r;       // re-stage relu output for pooling
        else      orow[n] = r;
    }
    if (POOL) {
        __syncthreads();
        const int Nh = N >> 1;
        const float* mh = mhalf + (size_t)b * Nh;
        float* prow = pool + ((size_t)b * Cout + co) * Nh;
        for (int np = tid; np < Nh; np += 1024) {
            float zm1 = (np > 0) ? srow[2 * np - 1] : 0.f;
            prow[np] = (zm1 + srow[2 * np] + srow[2 * np + 1]) * (1.f / 3.f) * mh[np];
        }
    }
}

// ---------------------------------------------------------------------------
// residual update: xc -= HSTEP * conv(z) * mask  (verbatim round 2)
// ---------------------------------------------------------------------------
template<int CIN, bool TR>
__global__ void __launch_bounds__(1024)
conv_axpy_kernel(const float* __restrict__ z, float* __restrict__ xc,
                 const float* __restrict__ K, int Cout, int N,
                 const float* __restrict__ mask)
{
    __shared__ float swt[CIN * 3];
    const int b   = blockIdx.x / Cout;
    const int co  = blockIdx.x % Cout;
    const int tid = threadIdx.x;

    for (int i = tid; i < CIN * 3; i += blockDim.x) {
        int ci = i / 3, k = i % 3;
        swt[i] = TR ? K[((size_t)ci * Cout + co) * 3 + (2 - k)]
                    : K[((size_t)co * CIN + ci) * 3 + k];
    }
    __syncthreads();

    const float* mrow = mask + (size_t)b * N;
    const float* zb   = z + (size_t)b * CIN * N;
    float* orow = xc + ((size_t)b * Cout + co) * N;
    for (int n = tid; n < N; n += 1024) {
        float acc = 0.f;
        const float* zr = zb + n;
        #pragma unroll 8
        for (int ci = 0; ci < CIN; ++ci, zr += N) {
            float xm = (n > 0)     ? zr[-1] : 0.f;
            float x0 = zr[0];
            float xp = (n < N - 1) ? zr[1]  : 0.f;
            acc = fmaf(swt[ci * 3 + 0], xm, acc);
            acc = fmaf(swt[ci * 3 + 1], x0, acc);
            acc = fmaf(swt[ci * 3 + 2], xp, acc);
        }
        orow[n] -= HSTEP * acc * mrow[n];
    }
}

// ---------------------------------------------------------------------------
// fused mask pipeline: DEN0, M1, DEN1, M2 (verbatim round 2)
// ---------------------------------------------------------------------------
__global__ void __launch_bounds__(256)
mask_prep_kernel(const float* __restrict__ mask, float* __restrict__ M1,
                 float* __restrict__ M2, float* __restrict__ d0, float* __restrict__ d1)
{
    __shared__ float sm1[1024];
    __shared__ float sredf[4];
    int b = blockIdx.x, tid = threadIdx.x;
    const float* mr = mask + (size_t)b * 2048;

    float s0 = 0.f;
    for (int n = tid; n < 2048; n += 256) s0 += mr[n];
    float t0 = block_sum1(s0, sredf);
    if (tid == 0) d0[b] = t0;

    for (int n = tid; n < 1024; n += 256) {
        float s = mr[2 * n];
        if (2 * n - 1 >= 0)   s += mr[2 * n - 1];
        if (2 * n + 1 < 2048) s += mr[2 * n + 1];
        float v = (s * (1.f / 3.f) >= 0.5f) ? 1.f : 0.f;
        sm1[n] = v;
        M1[(size_t)b * 1024 + n] = v;
    }
    __syncthreads();
    float s1 = 0.f;
    for (int n = tid; n < 1024; n += 256) s1 += sm1[n];
    float t1 = block_sum1(s1, sredf);
    if (tid == 0) d1[b] = t1;

    for (int n = tid; n < 512; n += 256) {
        float s = sm1[2 * n];
        if (2 * n - 1 >= 0)   s += sm1[2 * n - 1];
        if (2 * n + 1 < 1024) s += sm1[2 * n + 1];
        M2[(size_t)b * 512 + n] = (s * (1.f / 3.f) >= 0.5f) ? 1.f : 0.f;
    }
}

// ---------------------------------------------------------------------------
// fused: final W conv + coords override + dist_constraint (verbatim round 2)
// ---------------------------------------------------------------------------
__global__ void __launch_bounds__(1024)
dc_all_kernel(const float* __restrict__ xc32, const float* __restrict__ x,
              const float* __restrict__ W, const float* __restrict__ mask,
              const float* __restrict__ den, float* __restrict__ xout, int N)
{
    __shared__ float sX[3][2048];
    __shared__ float sD[3][2048];
    __shared__ float sM[2048];
    __shared__ unsigned long long smk[32];
    __shared__ float sW[96];

    const int b = blockIdx.x, tid = threadIdx.x;
    if (tid < 96) sW[tid] = W[tid];
    __syncthreads();

    const float* xb      = xc32 + (size_t)b * 32 * N;
    const float* flagrow = x + ((size_t)b * 24 + 23) * N;

    #pragma unroll
    for (int r = 0; r < 2; ++r) {
        int n = tid + r * 1024;
        float mk = mask[(size_t)b * N + n];
        float fl = flagrow[n];
        float v0 = 0.f, v1 = 0.f, v2 = 0.f;
        #pragma unroll 8
        for (int ci = 0; ci < 32; ++ci) {
            float xv = xb[(size_t)ci * N + n];
            v0 = fmaf(sW[0 * 32 + ci], xv, v0);
            v1 = fmaf(sW[1 * 32 + ci], xv, v1);
            v2 = fmaf(sW[2 * 32 + ci], xv, v2);
        }
        v0 *= mk; v1 *= mk; v2 *= mk;
        bool fixed = (fl == 1.f);
        if (fixed) {
            v0 = x[((size_t)b * 24 + 20) * N + n];
            v1 = x[((size_t)b * 24 + 21) * N + n];
            v2 = x[((size_t)b * 24 + 22) * N + n];
        }
        sX[0][n] = v0; sX[1][n] = v1; sX[2][n] = v2; sM[n] = mk;
        unsigned long long bm = __ballot(fixed);
        if ((tid & 63) == 0) smk[n >> 6] = bm;
    }
    __syncthreads();

    #pragma unroll
    for (int r = 0; r < 2; ++r) {
        int n = tid + r * 1024;
        if (n < N - 1) {
            float d0 = sX[0][n + 1] - sX[0][n];
            float d1 = sX[1][n + 1] - sX[1][n];
            float d2 = sX[2][n + 1] - sX[2][n];
            float d  = d0 * d0 + d1 * d1 + d2 * d2;
            bool avM = floorf((sM[n] + sM[n + 1]) * 0.5f) < 0.5f;
            if (avM) {
                sD[0][n] = 0.f; sD[1][n] = 0.f; sD[2][n] = 0.f;
            } else {
                float sq = sqrtf(d);
                sD[0][n] = (d0 / sq) * DCF;
                sD[1][n] = (d1 / sq) * DCF;
                sD[2][n] = (d2 / sq) * DCF;
            }
        }
    }
    __syncthreads();

    int len = (int)den[b];

    #pragma unroll
    for (int r = 0; r < 2; ++r) {
        int j  = tid + r * 1024;
        int cc = j >> 6, jl = j & 63;

        unsigned long long below = smk[cc] & (~0ull >> (63 - jl));
        int p = -1;
        if (below) p = (cc << 6) + 63 - __clzll(below);
        else {
            for (int c2 = cc - 1; c2 >= 0; --c2) {
                unsigned long long m = smk[c2];
                if (m) { p = (c2 << 6) + 63 - __clzll(m); break; }
            }
        }
        float l0, l1, l2, wl;
        if (p >= 0) {
            wl = (float)(j - p);
            l0 = sX[0][p]; l1 = sX[1][p]; l2 = sX[2][p];
            int kend = min(j, len - 1);
            for (int k = p; k < kend; ++k) {
                l0 += sD[0][k]; l1 += sD[1][k]; l2 += sD[2][k];
            }
        } else { wl = BIGF; l0 = sX[0][j]; l1 = sX[1][j]; l2 = sX[2][j]; }

        unsigned long long above = smk[cc] & (~0ull << jl);
        int q = -1;
        if (above) q = (cc << 6) + __ffsll(above) - 1;
        else {
            for (int c2 = cc + 1; c2 < 32; ++c2) {
                unsigned long long m = smk[c2];
                if (m) { q = (c2 << 6) + __ffsll(m) - 1; break; }
            }
        }
        float r0, r1, r2, wr;
        if (q >= 0) {
            wr = (float)(q - j);
            r0 = sX[0][q]; r1 = sX[1][q]; r2 = sX[2][q];
            for (int k = q - 1; k >= j; --k) {
                r0 -= sD[0][k]; r1 -= sD[1][k]; r2 -= sD[2][k];
            }
        } else { wr = BIGF; r0 = sX[0][j]; r1 = sX[1][j]; r2 = sX[2][j]; }

        float ws_ = wl + wr, cl, cr;
        if (ws_ == 0.f) { cl = 0.5f; cr = 0.5f; }
        else            { cl = wr / ws_; cr = wl / ws_; }
        float mk = sM[j];
        xout[((size_t)b * 3 + 0) * N + j] = (l0 * cl + r0 * cr) * mk;
        xout[((size_t)b * 3 + 1) * N + j] = (l1 * cl + r1 * cr) * mk;
        xout[((size_t)b * 3 + 2) * N + j] = (l2 * cl + r2 * cr) * mk;
    }
}

// ---------------------------------------------------------------------------
// pairwise distances (verbatim round 5): 2048 blocks, no LDS, coalesced
// nontemporal float4 stores; Y reads are L2-resident broadcasts.
// ---------------------------------------------------------------------------
__global__ void __launch_bounds__(256)
tr2dist_kernel(const float* __restrict__ Y, float* __restrict__ out)
{
    const int b    = blockIdx.x >> 8;     // 8 batches
    const int tile = blockIdx.x & 255;    // 256 tiles of 8 rows
    const int tid  = threadIdx.x;
    const float* yb = Y + (size_t)b * 6144;

    const int jA = tid * 4;               // cols 0..1023 (wave-contiguous)
    const int jB = 1024 + tid * 4;        // cols 1024..2047
    const float4 cA0 = *(const float4*)(yb + jA);
    const float4 cA1 = *(const float4*)(yb + 2048 + jA);
    const float4 cA2 = *(const float4*)(yb + 4096 + jA);
    const float4 cB0 = *(const float4*)(yb + jB);
    const float4 cB1 = *(const float4*)(yb + 2048 + jB);
    const float4 cB2 = *(const float4*)(yb + 4096 + jB);

    #pragma unroll
    for (int r = 0; r < 8; ++r) {
        const int i = tile * 8 + r;
        const float y0 = yb[i], y1 = yb[2048 + i], y2 = yb[4096 + i];
        v4f oA, oB;
        {
            float d0 = y0 - cA0.x, d1 = y1 - cA1.x, d2 = y2 - cA2.x;
            oA.x = sqrtf(fmaf(d0, d0, fmaf(d1, d1, fmaf(d2, d2, 1e-8f))));
            d0 = y0 - cA0.y; d1 = y1 - cA1.y; d2 = y2 - cA2.y;
            oA.y = sqrtf(fmaf(d0, d0, fmaf(d1, d1, fmaf(d2, d2, 1e-8f))));
            d0 = y0 - cA0.z; d1 = y1 - cA1.z; d2 = y2 - cA2.z;
            oA.z = sqrtf(fmaf(d0, d0, fmaf(d1, d1, fmaf(d2, d2, 1e-8f))));
            d0 = y0 - cA0.w; d1 = y1 - cA1.w; d2 = y2 - cA2.w;
            oA.w = sqrtf(fmaf(d0, d0, fmaf(d1, d1, fmaf(d2, d2, 1e-8f))));
        }
        {
            float d0 = y0 - cB0.x, d1 = y1 - cB1.x, d2 = y2 - cB2.x;
            oB.x = sqrtf(fmaf(d0, d0, fmaf(d1, d1, fmaf(d2, d2, 1e-8f))));
            d0 = y0 - cB0.y; d1 = y1 - cB1.y; d2 = y2 - cB2.y;
            oB.y = sqrtf(fmaf(d0, d0, fmaf(d1, d1, fmaf(d2, d2, 1e-8f))));
            d0 = y0 - cB0.z; d1 = y1 - cB1.z; d2 = y2 - cB2.z;
            oB.z = sqrtf(fmaf(d0, d0, fmaf(d1, d1, fmaf(d2, d2, 1e-8f))));
            d0 = y0 - cB0.w; d1 = y1 - cB1.w; d2 = y2 - cB2.w;
            oB.w = sqrtf(fmaf(d0, d0, fmaf(d1, d1, fmaf(d2, d2, 1e-8f))));
        }
        float* orow = out + ((size_t)b * 2048 + i) * 2048;
        __builtin_nontemporal_store(oA, (v4f*)(orow + jA));
        __builtin_nontemporal_store(oB, (v4f*)(orow + jB));
    }
}

// ---------------------------------------------------------------------------
// launch (24 dispatches)
// ---------------------------------------------------------------------------
extern "C" void kernel_launch(void* const* d_in, const int* in_sizes, int n_in,
                              void* d_out, int out_size, void* d_ws, size_t ws_size,
                              hipStream_t stream)
{
    const float* x    = (const float*)d_in[0];
    const float* mask = (const float*)d_in[1];
    const float* K0   = (const float*)d_in[2];
    const float* K1   = (const float*)d_in[3];
    const float* K2   = (const float*)d_in[4];
    const float* K3   = (const float*)d_in[5];
    const float* K4   = (const float*)d_in[6];
    const float* K5   = (const float*)d_in[7];
    const float* K6   = (const float*)d_in[8];
    const float* W    = (const float*)d_in[9];
    float* out = (float*)d_out;
    float* ws  = (float*)d_ws;
    (void)in_sizes; (void)n_in; (void)out_size; (void)ws_size;

    const int B = 8, N = 2048;
    size_t off = 0;
    auto alloc = [&](size_t nf) { float* p = ws + off; off += nf; return p; };

    float* M1   = alloc((size_t)B * 1024);
    float* M2   = alloc((size_t)B * 512);
    float* DEN0 = alloc(8);
    float* DEN1 = alloc(8);
    float* BUF0 = alloc(1048576);
    float* BUF1 = alloc(1048576);
    float* BUF2 = alloc(1048576);
    float* BUF3 = alloc(1048576);

    float* XOUT = out + (size_t)B * N * N;   // xout section of output
    float* NUL  = nullptr;

    // masks + denominators (fused)
    mask_prep_kernel<<<8, 256, 0, stream>>>(mask, M1, M2, DEN0, DEN1);

    // layer 0
    conv_in_relu_kernel<24, false, false, false><<<B * 32, 1024, 0, stream>>>(x, BUF0, K0, 32, 2048, mask, DEN0, NUL, NUL, NUL);

    // down i=1 (K1), i=2 (K2): residual
    conv_in_relu_kernel<32, false, false, false><<<B * 32, 1024, 0, stream>>>(BUF0, BUF1, K1, 32, 2048, mask, DEN0, NUL, NUL, NUL);
    conv_axpy_kernel<32, true><<<B * 32, 1024, 0, stream>>>(BUF1, BUF0, K1, 32, 2048, mask);
    conv_in_relu_kernel<32, false, false, false><<<B * 32, 1024, 0, stream>>>(BUF0, BUF1, K2, 32, 2048, mask, DEN0, NUL, NUL, NUL);
    conv_axpy_kernel<32, true><<<B * 32, 1024, 0, stream>>>(BUF1, BUF0, K2, 32, 2048, mask);

    // down i=3 (K3, 32->64) + FUSED pool -> BUF2 (64@1024); BUF0 = skip0
    conv_in_relu_kernel<32, false, false, true><<<B * 64, 1024, 0, stream>>>(BUF0, NUL, K3, 64, 2048, mask, DEN0, NUL, BUF2, M1);

    // down i=4 (K4), i=5 (K5): residual @1024
    conv_in_relu_kernel<64, false, false, false><<<B * 64, 1024, 0, stream>>>(BUF2, BUF1, K4, 64, 1024, M1, DEN1, NUL, NUL, NUL);
    conv_axpy_kernel<64, true><<<B * 64, 1024, 0, stream>>>(BUF1, BUF2, K4, 64, 1024, M1);
    conv_in_relu_kernel<64, false, false, false><<<B * 64, 1024, 0, stream>>>(BUF2, BUF1, K5, 64, 1024, M1, DEN1, NUL, NUL, NUL);
    conv_axpy_kernel<64, true><<<B * 64, 1024, 0, stream>>>(BUF1, BUF2, K5, 64, 1024, M1);

    // down i=6 (K6, 64->128) + FUSED pool -> BUF3 (128@512); BUF2 = skip1
    conv_in_relu_kernel<64, false, false, true><<<B * 128, 1024, 0, stream>>>(BUF2, NUL, K6, 128, 1024, M1, DEN1, NUL, BUF3, M2);

    // up i=6: FUSED upsample (BUF3 128@512 -> @1024) + convT K6 + IN + relu + skip(BUF2)
    conv_in_relu_kernel<128, true, true, false><<<B * 64, 1024, 0, stream>>>(BUF3, BUF1, K6, 64, 1024, M1, DEN1, BUF2, NUL, NUL);

    // up i=5 (K5), i=4 (K4): residual with convT then conv
    conv_in_relu_kernel<64, true, false, false><<<B * 64, 1024, 0, stream>>>(BUF1, BUF2, K5, 64, 1024, M1, DEN1, NUL, NUL, NUL);
    conv_axpy_kernel<64, false><<<B * 64, 1024, 0, stream>>>(BUF2, BUF1, K5, 64, 1024, M1);
    conv_in_relu_kernel<64, true, false, false><<<B * 64, 1024, 0, stream>>>(BUF1, BUF2, K4, 64, 1024, M1, DEN1, NUL, NUL, NUL);
    conv_axpy_kernel<64, false><<<B * 64, 1024, 0, stream>>>(BUF2, BUF1, K4, 64, 1024, M1);

    // up i=3: FUSED upsample (BUF1 64@1024 -> @2048) + convT K3 + IN + relu + skip(BUF0)
    conv_in_relu_kernel<64, true, true, false><<<B * 32, 1024, 0, stream>>>(BUF1, BUF2, K3, 32, 2048, mask, DEN0, BUF0, NUL, NUL);

    // up i=2 (K2), i=1 (K1): residual
    conv_in_relu_kernel<32, true, false, false><<<B * 32, 1024, 0, stream>>>(BUF2, BUF1, K2, 32, 2048, mask, DEN0, NUL, NUL, NUL);
    conv_axpy_kernel<32, false><<<B * 32, 1024, 0, stream>>>(BUF1, BUF2, K2, 32, 2048, mask);
    conv_in_relu_kernel<32, true, false, false><<<B * 32, 1024, 0, stream>>>(BUF2, BUF1, K1, 32, 2048, mask, DEN0, NUL, NUL, NUL);
    conv_axpy_kernel<32, false><<<B * 32, 1024, 0, stream>>>(BUF1, BUF2, K1, 32, 2048, mask);

    // final W conv + coords override + dist_constraint, all in one kernel
    dc_all_kernel<<<8, 1024, 0, stream>>>(BUF2, x, W, mask, DEN0, XOUT, N);

    // pairwise distance matrix
    tr2dist_kernel<<<8 * 256, 256, 0, stream>>>(XOUT, out);
}

// Round 10
// 435.586 us; speedup vs baseline: 1.2477x; 1.2477x over previous
//
#include <hip/hip_runtime.h>
#include <math.h>

#define HSTEP 0.1f
#define EPS_IN 1e-5f
#define BIGF 1e10f
#define DCF 3.79f

typedef float v4f __attribute__((ext_vector_type(4)));

// ---------------------------------------------------------------------------
// helpers
// ---------------------------------------------------------------------------
__device__ inline float block_sum1(float v, float* sred) {
    #pragma unroll
    for (int off = 32; off > 0; off >>= 1) v += __shfl_down(v, off);
    int wid = threadIdx.x >> 6;
    int nw  = blockDim.x >> 6;
    if ((threadIdx.x & 63) == 0) sred[wid] = v;
    __syncthreads();
    float total = 0.f;
    for (int i = 0; i < nw; ++i) total += sred[i];
    __syncthreads();
    return total;
}

__device__ inline float2 block_sum2(float a, float b, float2* sred) {
    #pragma unroll
    for (int off = 32; off > 0; off >>= 1) {
        a += __shfl_down(a, off);
        b += __shfl_down(b, off);
    }
    int wid = threadIdx.x >> 6;
    int nw  = blockDim.x >> 6;
    if ((threadIdx.x & 63) == 0) sred[wid] = make_float2(a, b);
    __syncthreads();
    float ta = 0.f, tb = 0.f;
    for (int i = 0; i < nw; ++i) { ta += sred[i].x; tb += sred[i].y; }
    __syncthreads();
    return make_float2(ta, tb);
}

// ---------------------------------------------------------------------------
// fused conv (optionally transposed weights) * mask -> masked instance norm
// -> relu -> optional skip add -> optional fused avg-pool (POOL) with
// optional fused upsample-on-read (UPS).  One block (1024 thr) per (b, co).
// b = blockIdx & 7: batch->XCD affinity (8 batches, 8 XCDs) so each batch's
// input slab is fetched into ONE XCD's L2 and reused by all its co-blocks.
// ---------------------------------------------------------------------------
template<int CIN, bool TR, bool UPS, bool POOL>
__global__ void __launch_bounds__(1024)
conv_in_relu_kernel(const float* __restrict__ xin, float* __restrict__ out,
                    const float* __restrict__ K, int Cout, int N,
                    const float* __restrict__ mask, const float* __restrict__ denom,
                    const float* __restrict__ skip, float* __restrict__ pool,
                    const float* __restrict__ mhalf)
{
    __shared__ float srow[2048];
    __shared__ float swt[CIN * 3];
    __shared__ float2 sred[16];

    const int b   = blockIdx.x & 7;     // batch -> XCD affinity
    const int co  = blockIdx.x >> 3;
    const int tid = threadIdx.x;

    for (int i = tid; i < CIN * 3; i += blockDim.x) {
        int ci = i / 3, k = i % 3;
        swt[i] = TR ? K[((size_t)ci * Cout + co) * 3 + (2 - k)]
                    : K[((size_t)co * CIN + ci) * 3 + k];
    }
    __syncthreads();

    const int srcw = UPS ? (N >> 1) : N;
    const float* mrow = mask + (size_t)b * N;
    const float* xb   = xin + (size_t)b * CIN * srcw;
    float lsum = 0.f, lss = 0.f;
    for (int n = tid; n < N; n += 1024) {
        // hoisted mask values / half-res indices for the UPS path
        float m0 = mrow[n], mm = 0.f, mp = 0.f;
        int ih = 0, ihm = 0, ihp = 0;
        if (UPS) {
            mm = (n > 0)     ? mrow[n - 1] : 0.f;
            mp = (n < N - 1) ? mrow[n + 1] : 0.f;
            ih = n >> 1; ihm = (n - 1) >> 1; ihp = (n + 1) >> 1;
        }
        float acc = 0.f;
        #pragma unroll 8
        for (int ci = 0; ci < CIN; ++ci) {
            const float* src = xb + (size_t)ci * srcw;
            float xm, x0, xp;
            if (!UPS) {
                xm = (n > 0)     ? src[n - 1] : 0.f;
                x0 = src[n];
                xp = (n < N - 1) ? src[n + 1] : 0.f;
            } else {
                x0 = src[ih] * m0;
                xm = (n > 0)     ? src[ihm] * mm : 0.f;
                xp = (n < N - 1) ? src[ihp] * mp : 0.f;
            }
            acc = fmaf(swt[ci * 3 + 0], xm, acc);
            acc = fmaf(swt[ci * 3 + 1], x0, acc);
            acc = fmaf(swt[ci * 3 + 2], xp, acc);
        }
        float v = acc * m0;
        srow[n] = v;
        lsum += v;
        lss  += v * v;
    }
    float dn = denom[b];
    float2 s = block_sum2(lsum, lss, sred);
    float mean = s.x / dn;
    float var  = s.y / dn - mean * mean;
    float inv  = 1.f / sqrtf(var + EPS_IN);

    float* orow = POOL ? nullptr : out + ((size_t)b * Cout + co) * N;
    const float* skrow = skip ? skip + ((size_t)b * Cout + co) * N : nullptr;
    for (int n = tid; n < N; n += 1024) {
        float mk = mrow[n];
        float zv = (srow[n] - mean * mk) * inv;
        float r  = fmaxf(zv, 0.f);
        if (skrow) r += skrow[n];
        if (POOL) srow[n] = r;       // re-stage relu output for pooling
        else      orow[n] = r;
    }
    if (POOL) {
        __syncthreads();
        const int Nh = N >> 1;
        const float* mh = mhalf + (size_t)b * Nh;
        float* prow = pool + ((size_t)b * Cout + co) * Nh;
        for (int np = tid; np < Nh; np += 1024) {
            float zm1 = (np > 0) ? srow[2 * np - 1] : 0.f;
            prow[np] = (zm1 + srow[2 * np] + srow[2 * np + 1]) * (1.f / 3.f) * mh[np];
        }
    }
}

// ---------------------------------------------------------------------------
// residual update: xc -= HSTEP * conv(z) * mask  (XCD-affine b)
// ---------------------------------------------------------------------------
template<int CIN, bool TR>
__global__ void __launch_bounds__(1024)
conv_axpy_kernel(const float* __restrict__ z, float* __restrict__ xc,
                 const float* __restrict__ K, int Cout, int N,
                 const float* __restrict__ mask)
{
    __shared__ float swt[CIN * 3];
    const int b   = blockIdx.x & 7;     // batch -> XCD affinity
    const int co  = blockIdx.x >> 3;
    const int tid = threadIdx.x;

    for (int i = tid; i < CIN * 3; i += blockDim.x) {
        int ci = i / 3, k = i % 3;
        swt[i] = TR ? K[((size_t)ci * Cout + co) * 3 + (2 - k)]
                    : K[((size_t)co * CIN + ci) * 3 + k];
    }
    __syncthreads();

    const float* mrow = mask + (size_t)b * N;
    const float* zb   = z + (size_t)b * CIN * N;
    float* orow = xc + ((size_t)b * Cout + co) * N;
    for (int n = tid; n < N; n += 1024) {
        float acc = 0.f;
        const float* zr = zb + n;
        #pragma unroll 8
        for (int ci = 0; ci < CIN; ++ci, zr += N) {
            float xm = (n > 0)     ? zr[-1] : 0.f;
            float x0 = zr[0];
            float xp = (n < N - 1) ? zr[1]  : 0.f;
            acc = fmaf(swt[ci * 3 + 0], xm, acc);
            acc = fmaf(swt[ci * 3 + 1], x0, acc);
            acc = fmaf(swt[ci * 3 + 2], xp, acc);
        }
        orow[n] -= HSTEP * acc * mrow[n];
    }
}

// ---------------------------------------------------------------------------
// fused mask pipeline: DEN0, M1, DEN1, M2 (verbatim round 2)
// ---------------------------------------------------------------------------
__global__ void __launch_bounds__(256)
mask_prep_kernel(const float* __restrict__ mask, float* __restrict__ M1,
                 float* __restrict__ M2, float* __restrict__ d0, float* __restrict__ d1)
{
    __shared__ float sm1[1024];
    __shared__ float sredf[4];
    int b = blockIdx.x, tid = threadIdx.x;
    const float* mr = mask + (size_t)b * 2048;

    float s0 = 0.f;
    for (int n = tid; n < 2048; n += 256) s0 += mr[n];
    float t0 = block_sum1(s0, sredf);
    if (tid == 0) d0[b] = t0;

    for (int n = tid; n < 1024; n += 256) {
        float s = mr[2 * n];
        if (2 * n - 1 >= 0)   s += mr[2 * n - 1];
        if (2 * n + 1 < 2048) s += mr[2 * n + 1];
        float v = (s * (1.f / 3.f) >= 0.5f) ? 1.f : 0.f;
        sm1[n] = v;
        M1[(size_t)b * 1024 + n] = v;
    }
    __syncthreads();
    float s1 = 0.f;
    for (int n = tid; n < 1024; n += 256) s1 += sm1[n];
    float t1 = block_sum1(s1, sredf);
    if (tid == 0) d1[b] = t1;

    for (int n = tid; n < 512; n += 256) {
        float s = sm1[2 * n];
        if (2 * n - 1 >= 0)   s += sm1[2 * n - 1];
        if (2 * n + 1 < 1024) s += sm1[2 * n + 1];
        M2[(size_t)b * 512 + n] = (s * (1.f / 3.f) >= 0.5f) ? 1.f : 0.f;
    }
}

// ---------------------------------------------------------------------------
// fused: final W conv + coords override + dist_constraint (verbatim round 2)
// ---------------------------------------------------------------------------
__global__ void __launch_bounds__(1024)
dc_all_kernel(const float* __restrict__ xc32, const float* __restrict__ x,
              const float* __restrict__ W, const float* __restrict__ mask,
              const float* __restrict__ den, float* __restrict__ xout, int N)
{
    __shared__ float sX[3][2048];
    __shared__ float sD[3][2048];
    __shared__ float sM[2048];
    __shared__ unsigned long long smk[32];
    __shared__ float sW[96];

    const int b = blockIdx.x, tid = threadIdx.x;
    if (tid < 96) sW[tid] = W[tid];
    __syncthreads();

    const float* xb      = xc32 + (size_t)b * 32 * N;
    const float* flagrow = x + ((size_t)b * 24 + 23) * N;

    #pragma unroll
    for (int r = 0; r < 2; ++r) {
        int n = tid + r * 1024;
        float mk = mask[(size_t)b * N + n];
        float fl = flagrow[n];
        float v0 = 0.f, v1 = 0.f, v2 = 0.f;
        #pragma unroll 8
        for (int ci = 0; ci < 32; ++ci) {
            float xv = xb[(size_t)ci * N + n];
            v0 = fmaf(sW[0 * 32 + ci], xv, v0);
            v1 = fmaf(sW[1 * 32 + ci], xv, v1);
            v2 = fmaf(sW[2 * 32 + ci], xv, v2);
        }
        v0 *= mk; v1 *= mk; v2 *= mk;
        bool fixed = (fl == 1.f);
        if (fixed) {
            v0 = x[((size_t)b * 24 + 20) * N + n];
            v1 = x[((size_t)b * 24 + 21) * N + n];
            v2 = x[((size_t)b * 24 + 22) * N + n];
        }
        sX[0][n] = v0; sX[1][n] = v1; sX[2][n] = v2; sM[n] = mk;
        unsigned long long bm = __ballot(fixed);
        if ((tid & 63) == 0) smk[n >> 6] = bm;
    }
    __syncthreads();

    #pragma unroll
    for (int r = 0; r < 2; ++r) {
        int n = tid + r * 1024;
        if (n < N - 1) {
            float d0 = sX[0][n + 1] - sX[0][n];
            float d1 = sX[1][n + 1] - sX[1][n];
            float d2 = sX[2][n + 1] - sX[2][n];
            float d  = d0 * d0 + d1 * d1 + d2 * d2;
            bool avM = floorf((sM[n] + sM[n + 1]) * 0.5f) < 0.5f;
            if (avM) {
                sD[0][n] = 0.f; sD[1][n] = 0.f; sD[2][n] = 0.f;
            } else {
                float sq = sqrtf(d);
                sD[0][n] = (d0 / sq) * DCF;
                sD[1][n] = (d1 / sq) * DCF;
                sD[2][n] = (d2 / sq) * DCF;
            }
        }
    }
    __syncthreads();

    int len = (int)den[b];

    #pragma unroll
    for (int r = 0; r < 2; ++r) {
        int j  = tid + r * 1024;
        int cc = j >> 6, jl = j & 63;

        unsigned long long below = smk[cc] & (~0ull >> (63 - jl));
        int p = -1;
        if (below) p = (cc << 6) + 63 - __clzll(below);
        else {
            for (int c2 = cc - 1; c2 >= 0; --c2) {
                unsigned long long m = smk[c2];
                if (m) { p = (c2 << 6) + 63 - __clzll(m); break; }
            }
        }
        float l0, l1, l2, wl;
        if (p >= 0) {
            wl = (float)(j - p);
            l0 = sX[0][p]; l1 = sX[1][p]; l2 = sX[2][p];
            int kend = min(j, len - 1);
            for (int k = p; k < kend; ++k) {
                l0 += sD[0][k]; l1 += sD[1][k]; l2 += sD[2][k];
            }
        } else { wl = BIGF; l0 = sX[0][j]; l1 = sX[1][j]; l2 = sX[2][j]; }

        unsigned long long above = smk[cc] & (~0ull << jl);
        int q = -1;
        if (above) q = (cc << 6) + __ffsll(above) - 1;
        else {
            for (int c2 = cc + 1; c2 < 32; ++c2) {
                unsigned long long m = smk[c2];
                if (m) { q = (c2 << 6) + __ffsll(m) - 1; break; }
            }
        }
        float r0, r1, r2, wr;
        if (q >= 0) {
            wr = (float)(q - j);
            r0 = sX[0][q]; r1 = sX[1][q]; r2 = sX[2][q];
            for (int k = q - 1; k >= j; --k) {
                r0 -= sD[0][k]; r1 -= sD[1][k]; r2 -= sD[2][k];
            }
        } else { wr = BIGF; r0 = sX[0][j]; r1 = sX[1][j]; r2 = sX[2][j]; }

        float ws_ = wl + wr, cl, cr;
        if (ws_ == 0.f) { cl = 0.5f; cr = 0.5f; }
        else            { cl = wr / ws_; cr = wl / ws_; }
        float mk = sM[j];
        xout[((size_t)b * 3 + 0) * N + j] = (l0 * cl + r0 * cr) * mk;
        xout[((size_t)b * 3 + 1) * N + j] = (l1 * cl + r1 * cr) * mk;
        xout[((size_t)b * 3 + 2) * N + j] = (l2 * cl + r2 * cr) * mk;
    }
}

// ---------------------------------------------------------------------------
// pairwise distances (verbatim round 5): 2048 blocks, no LDS, coalesced
// nontemporal float4 stores; Y reads are L2-resident broadcasts.
// ---------------------------------------------------------------------------
__global__ void __launch_bounds__(256)
tr2dist_kernel(const float* __restrict__ Y, float* __restrict__ out)
{
    const int b    = blockIdx.x >> 8;     // 8 batches
    const int tile = blockIdx.x & 255;    // 256 tiles of 8 rows
    const int tid  = threadIdx.x;
    const float* yb = Y + (size_t)b * 6144;

    const int jA = tid * 4;               // cols 0..1023 (wave-contiguous)
    const int jB = 1024 + tid * 4;        // cols 1024..2047
    const float4 cA0 = *(const float4*)(yb + jA);
    const float4 cA1 = *(const float4*)(yb + 2048 + jA);
    const float4 cA2 = *(const float4*)(yb + 4096 + jA);
    const float4 cB0 = *(const float4*)(yb + jB);
    const float4 cB1 = *(const float4*)(yb + 2048 + jB);
    const float4 cB2 = *(const float4*)(yb + 4096 + jB);

    #pragma unroll
    for (int r = 0; r < 8; ++r) {
        const int i = tile * 8 + r;
        const float y0 = yb[i], y1 = yb[2048 + i], y2 = yb[4096 + i];
        v4f oA, oB;
        {
            float d0 = y0 - cA0.x, d1 = y1 - cA1.x, d2 = y2 - cA2.x;
            oA.x = sqrtf(fmaf(d0, d0, fmaf(d1, d1, fmaf(d2, d2, 1e-8f))));
            d0 = y0 - cA0.y; d1 = y1 - cA1.y; d2 = y2 - cA2.y;
            oA.y = sqrtf(fmaf(d0, d0, fmaf(d1, d1, fmaf(d2, d2, 1e-8f))));
            d0 = y0 - cA0.z; d1 = y1 - cA1.z; d2 = y2 - cA2.z;
            oA.z = sqrtf(fmaf(d0, d0, fmaf(d1, d1, fmaf(d2, d2, 1e-8f))));
            d0 = y0 - cA0.w; d1 = y1 - cA1.w; d2 = y2 - cA2.w;
            oA.w = sqrtf(fmaf(d0, d0, fmaf(d1, d1, fmaf(d2, d2, 1e-8f))));
        }
        {
            float d0 = y0 - cB0.x, d1 = y1 - cB1.x, d2 = y2 - cB2.x;
            oB.x = sqrtf(fmaf(d0, d0, fmaf(d1, d1, fmaf(d2, d2, 1e-8f))));
            d0 = y0 - cB0.y; d1 = y1 - cB1.y; d2 = y2 - cB2.y;
            oB.y = sqrtf(fmaf(d0, d0, fmaf(d1, d1, fmaf(d2, d2, 1e-8f))));
            d0 = y0 - cB0.z; d1 = y1 - cB1.z; d2 = y2 - cB2.z;
            oB.z = sqrtf(fmaf(d0, d0, fmaf(d1, d1, fmaf(d2, d2, 1e-8f))));
            d0 = y0 - cB0.w; d1 = y1 - cB1.w; d2 = y2 - cB2.w;
            oB.w = sqrtf(fmaf(d0, d0, fmaf(d1, d1, fmaf(d2, d2, 1e-8f))));
        }
        float* orow = out + ((size_t)b * 2048 + i) * 2048;
        __builtin_nontemporal_store(oA, (v4f*)(orow + jA));
        __builtin_nontemporal_store(oB, (v4f*)(orow + jB));
    }
}

// ---------------------------------------------------------------------------
// launch (24 dispatches)
// ---------------------------------------------------------------------------
extern "C" void kernel_launch(void* const* d_in, const int* in_sizes, int n_in,
                              void* d_out, int out_size, void* d_ws, size_t ws_size,
                              hipStream_t stream)
{
    const float* x    = (const float*)d_in[0];
    const float* mask = (const float*)d_in[1];
    const float* K0   = (const float*)d_in[2];
    const float* K1   = (const float*)d_in[3];
    const float* K2   = (const float*)d_in[4];
    const float* K3   = (const float*)d_in[5];
    const float* K4   = (const float*)d_in[6];
    const float* K5   = (const float*)d_in[7];
    const float* K6   = (const float*)d_in[8];
    const float* W    = (const float*)d_in[9];
    float* out = (float*)d_out;
    float* ws  = (float*)d_ws;
    (void)in_sizes; (void)n_in; (void)out_size; (void)ws_size;

    const int B = 8, N = 2048;
    size_t off = 0;
    auto alloc = [&](size_t nf) { float* p = ws + off; off += nf; return p; };

    float* M1   = alloc((size_t)B * 1024);
    float* M2   = alloc((size_t)B * 512);
    float* DEN0 = alloc(8);
    float* DEN1 = alloc(8);
    float* BUF0 = alloc(1048576);
    float* BUF1 = alloc(1048576);
    float* BUF2 = alloc(1048576);
    float* BUF3 = alloc(1048576);

    float* XOUT = out + (size_t)B * N * N;   // xout section of output
    float* NUL  = nullptr;

    // masks + denominators (fused)
    mask_prep_kernel<<<8, 256, 0, stream>>>(mask, M1, M2, DEN0, DEN1);

    // layer 0
    conv_in_relu_kernel<24, false, false, false><<<B * 32, 1024, 0, stream>>>(x, BUF0, K0, 32, 2048, mask, DEN0, NUL, NUL, NUL);

    // down i=1 (K1), i=2 (K2): residual
    conv_in_relu_kernel<32, false, false, false><<<B * 32, 1024, 0, stream>>>(BUF0, BUF1, K1, 32, 2048, mask, DEN0, NUL, NUL, NUL);
    conv_axpy_kernel<32, true><<<B * 32, 1024, 0, stream>>>(BUF1, BUF0, K1, 32, 2048, mask);
    conv_in_relu_kernel<32, false, false, false><<<B * 32, 1024, 0, stream>>>(BUF0, BUF1, K2, 32, 2048, mask, DEN0, NUL, NUL, NUL);
    conv_axpy_kernel<32, true><<<B * 32, 1024, 0, stream>>>(BUF1, BUF0, K2, 32, 2048, mask);

    // down i=3 (K3, 32->64) + FUSED pool -> BUF2 (64@1024); BUF0 = skip0
    conv_in_relu_kernel<32, false, false, true><<<B * 64, 1024, 0, stream>>>(BUF0, NUL, K3, 64, 2048, mask, DEN0, NUL, BUF2, M1);

    // down i=4 (K4), i=5 (K5): residual @1024
    conv_in_relu_kernel<64, false, false, false><<<B * 64, 1024, 0, stream>>>(BUF2, BUF1, K4, 64, 1024, M1, DEN1, NUL, NUL, NUL);
    conv_axpy_kernel<64, true><<<B * 64, 1024, 0, stream>>>(BUF1, BUF2, K4, 64, 1024, M1);
    conv_in_relu_kernel<64, false, false, false><<<B * 64, 1024, 0, stream>>>(BUF2, BUF1, K5, 64, 1024, M1, DEN1, NUL, NUL, NUL);
    conv_axpy_kernel<64, true><<<B * 64, 1024, 0, stream>>>(BUF1, BUF2, K5, 64, 1024, M1);

    // down i=6 (K6, 64->128) + FUSED pool -> BUF3 (128@512); BUF2 = skip1
    conv_in_relu_kernel<64, false, false, true><<<B * 128, 1024, 0, stream>>>(BUF2, NUL, K6, 128, 1024, M1, DEN1, NUL, BUF3, M2);

    // up i=6: FUSED upsample (BUF3 128@512 -> @1024) + convT K6 + IN + relu + skip(BUF2)
    conv_in_relu_kernel<128, true, true, false><<<B * 64, 1024, 0, stream>>>(BUF3, BUF1, K6, 64, 1024, M1, DEN1, BUF2, NUL, NUL);

    // up i=5 (K5), i=4 (K4): residual with convT then conv
    conv_in_relu_kernel<64, true, false, false><<<B * 64, 1024, 0, stream>>>(BUF1, BUF2, K5, 64, 1024, M1, DEN1, NUL, NUL, NUL);
    conv_axpy_kernel<64, false><<<B * 64, 1024, 0, stream>>>(BUF2, BUF1, K5, 64, 1024, M1);
    conv_in_relu_kernel<64, true, false, false><<<B * 64, 1024, 0, stream>>>(BUF1, BUF2, K4, 64, 1024, M1, DEN1, NUL, NUL, NUL);
    conv_axpy_kernel<64, false><<<B * 64, 1024, 0, stream>>>(BUF2, BUF1, K4, 64, 1024, M1);

    // up i=3: FUSED upsample (BUF1 64@1024 -> @2048) + convT K3 + IN + relu + skip(BUF0)
    conv_in_relu_kernel<64, true, true, false><<<B * 32, 1024, 0, stream>>>(BUF1, BUF2, K3, 32, 2048, mask, DEN0, BUF0, NUL, NUL);

    // up i=2 (K2), i=1 (K1): residual
    conv_in_relu_kernel<32, true, false, false><<<B * 32, 1024, 0, stream>>>(BUF2, BUF1, K2, 32, 2048, mask, DEN0, NUL, NUL, NUL);
    conv_axpy_kernel<32, false><<<B * 32, 1024, 0, stream>>>(BUF1, BUF2, K2, 32, 2048, mask);
    conv_in_relu_kernel<32, true, false, false><<<B * 32, 1024, 0, stream>>>(BUF2, BUF1, K1, 32, 2048, mask, DEN0, NUL, NUL, NUL);
    conv_axpy_kernel<32, false><<<B * 32, 1024, 0, stream>>>(BUF1, BUF2, K1, 32, 2048, mask);

    // final W conv + coords override + dist_constraint, all in one kernel
    dc_all_kernel<<<8, 1024, 0, stream>>>(BUF2, x, W, mask, DEN0, XOUT, N);

    // pairwise distance matrix
    tr2dist_kernel<<<8 * 256, 256, 0, stream>>>(XOUT, out);
}